// Round 17
// baseline (1067.385 us; speedup 1.0000x reference)
//
#include <hip/hip_runtime.h>
#include <hip/hip_bf16.h>
#include <stdint.h>

#define G_ 4
#define E_ 16
#define C_ 2048
#define H_ 512
#define F_ 2048

typedef __attribute__((ext_vector_type(8))) short bf16x8;
typedef __attribute__((ext_vector_type(4))) float f32x4;
typedef uint32_t u32_glb __attribute__((address_space(1)));
typedef uint32_t u32_lds __attribute__((address_space(3)));

__device__ __forceinline__ ushort f2bf(float f){
  uint u = __float_as_uint(f);
  return (ushort)((u + 0x7FFFu + ((u >> 16) & 1u)) >> 16);  // RNE
}

__device__ __forceinline__ bf16x8 pack8(f32x4 a, f32x4 b){
  union { bf16x8 v; uint u[4]; } p;
  p.u[0] = (uint)f2bf(a[0]) | ((uint)f2bf(a[1]) << 16);
  p.u[1] = (uint)f2bf(a[2]) | ((uint)f2bf(a[3]) << 16);
  p.u[2] = (uint)f2bf(b[0]) | ((uint)f2bf(b[1]) << 16);
  p.u[3] = (uint)f2bf(b[2]) | ((uint)f2bf(b[3]) << 16);
  return p.v;
}

// fast GELU (R10-validated: absmax 1.95e-3 same as exact-erf version)
__device__ __forceinline__ float geluf(float t){
  float y = 0.7978845608f * t * (1.0f + 0.044715f * t * t);
  y = fminf(fmaxf(y, -9.0f), 9.0f);
  float z = __expf(-2.0f * y);
  return t * __builtin_amdgcn_rcpf(1.0f + z);
}

// transpose + fp32->bf16 convert: src [E][R][C] fp32 -> dst [E][C][R] bf16
__global__ void transpose_cvt(const float* __restrict__ src, ushort* __restrict__ dst,
                              int R, int C){
  __shared__ float tile[64][65];
  int c0 = blockIdx.x * 64, r0 = blockIdx.y * 64, e = blockIdx.z;
  int tx = threadIdx.x & 63, ty = threadIdx.x >> 6;   // 256 threads
  const float* s = src + (size_t)e * R * C;
  #pragma unroll
  for (int it = 0; it < 16; ++it){
    int row = ty + it * 4;
    tile[row][tx] = s[(size_t)(r0 + row) * C + (c0 + tx)];
  }
  __syncthreads();
  ushort* d = dst + (size_t)e * C * R;
  #pragma unroll
  for (int it = 0; it < 16; ++it){
    int row = ty + it * 4;
    d[(size_t)(c0 + row) * R + (r0 + tx)] = f2bf(tile[tx][row]);
  }
}

// X fp32 -> bf16, straight copy (memory-bound)
__global__ __launch_bounds__(256) void cvt_x(const float* __restrict__ x,
                                             ushort* __restrict__ xbf){
  const size_t stride = (size_t)gridDim.x * 256 * 16;
  size_t base = ((size_t)blockIdx.x * 256 + threadIdx.x) * 16;
  for (size_t i = base; i < (size_t)G_ * E_ * C_ * H_; i += stride){
    f32x4 a0 = *(const f32x4*)(x + i);
    f32x4 a1 = *(const f32x4*)(x + i + 4);
    f32x4 a2 = *(const f32x4*)(x + i + 8);
    f32x4 a3 = *(const f32x4*)(x + i + 12);
    *(bf16x8*)(xbf + i)     = pack8(a0, a1);
    *(bf16x8*)(xbf + i + 8) = pack8(a2, a3);
  }
}

#define TR_P 132   // transpose scratch pitch (ushorts): banks spread, 2-way max

// ====== GEMM1 (2 n-tiles/block): h1 = gelu(Xe @ w1t^T + b1), m97 mainloop ======
__device__ __forceinline__ void dev_gemm1_pair(
    ushort* sA, ushort* sB, ushort* sTr,
    const ushort* __restrict__ xbf, const float* __restrict__ b1,
    const ushort* __restrict__ w1t, ushort* __restrict__ h1slab,
    int e, int m0, int n0base){
  const int tid  = threadIdx.x;
  const int lane = tid & 63;
  const int wv   = tid >> 6;
  const int l15  = lane & 15;
  const int lg   = lane >> 4;
  const int wm   = wv >> 1;
  const int wn   = wv & 1;
  const ushort* w1e = w1t + (size_t)e * F_ * H_;
  const ushort* xe  = xbf + (((size_t)(m0 >> 11) * 16 + e) * 2048 + (m0 & 2047)) * H_;

  f32x4 acc[4][4];
  #pragma unroll
  for (int a = 0; a < 4; ++a)
    #pragma unroll
    for (int b = 0; b < 4; ++b) acc[a][b] = (f32x4){0.f,0.f,0.f,0.f};

  #define G1_STAGE(N0C, KK, NB) {                                                \
    _Pragma("unroll")                                                            \
    for (int i = 0; i < 2; ++i){                                                 \
      const int r = wv * 16 + i * 64 + (lane >> 2);                              \
      const ushort* ga = xe + (size_t)r * H_ + (KK) * 32 + (lane & 3) * 8;       \
      __builtin_amdgcn_global_load_lds((const u32_glb*)(uintptr_t)ga,            \
          (u32_lds*)(uintptr_t)(sA + (NB) * 4096 + r * 32), 16, 0, 0);           \
      const ushort* gb = w1e + (size_t)((N0C) + r) * H_ + (KK) * 32 + (lane & 3) * 8;\
      __builtin_amdgcn_global_load_lds((const u32_glb*)(uintptr_t)gb,            \
          (u32_lds*)(uintptr_t)(sB + (NB) * 4096 + r * 32), 16, 0, 0);           \
    } }

  G1_STAGE(n0base, 0, 0)
  __syncthreads();

  #pragma unroll
  for (int nt = 0; nt < 2; ++nt){
    const int n0c = n0base + nt * 128;
    for (int kk = 0; kk < 16; ++kk){
      const int cur = kk & 1, nxt = cur ^ 1;
      if (kk < 15){ G1_STAGE(n0c, kk + 1, nxt) }
      bf16x8 af[4], bfr[4];
      #pragma unroll
      for (int mf = 0; mf < 4; ++mf)
        af[mf] = *(const bf16x8*)(sA + cur * 4096 + (wm * 64 + mf * 16 + l15) * 32 + lg * 8);
      #pragma unroll
      for (int nf = 0; nf < 4; ++nf)
        bfr[nf] = *(const bf16x8*)(sB + cur * 4096 + (wn * 64 + nf * 16 + l15) * 32 + lg * 8);
      __builtin_amdgcn_s_setprio(1);
      #pragma unroll
      for (int mf = 0; mf < 4; ++mf)
        #pragma unroll
        for (int nf = 0; nf < 4; ++nf)
          acc[mf][nf] = __builtin_amdgcn_mfma_f32_16x16x32_bf16(af[mf], bfr[nf], acc[mf][nf], 0, 0, 0);
      __builtin_amdgcn_s_setprio(0);
      __syncthreads();
    }
    // issue next tile's k0 DMA now; its drain lands at the next barrier,
    // hidden under the gelu+transpose write phase below.
    if (nt == 0){ G1_STAGE(n0base + 128, 0, 0) }

    // ---- epilogue: gelu -> LDS transpose (per wm-half) -> 256B-coalesced stores
    float bb[4];
    #pragma unroll
    for (int nf = 0; nf < 4; ++nf)
      bb[nf] = b1[e * F_ + n0c + wn * 64 + nf * 16 + l15];
    #pragma unroll
    for (int rr = 0; rr < 2; ++rr){
      if (wm == rr){
        #pragma unroll
        for (int mf = 0; mf < 4; ++mf)
          #pragma unroll
          for (int nf = 0; nf < 4; ++nf)
            #pragma unroll
            for (int i = 0; i < 4; ++i)
              sTr[(mf * 16 + lg * 4 + i) * TR_P + wn * 64 + nf * 16 + l15] =
                  f2bf(geluf(acc[mf][nf][i] + bb[nf]));
      }
      __syncthreads();
      #pragma unroll
      for (int u = 0; u < 4; ++u){
        const int unit = u * 256 + tid;
        const int rl = unit >> 4, seg = unit & 15;
        bf16x8 vv = *(const bf16x8*)(&sTr[rl * TR_P + seg * 8]);
        *(bf16x8*)(&h1slab[(size_t)(m0 + rr * 64 + rl) * F_ + n0c + seg * 8]) = vv;
      }
      __syncthreads();
    }
    if (nt == 0){
      #pragma unroll
      for (int a = 0; a < 4; ++a)
        #pragma unroll
        for (int b = 0; b < 4; ++b) acc[a][b] = (f32x4){0.f,0.f,0.f,0.f};
    }
  }
  #undef G1_STAGE
}

// ====== GEMM2: out_e = h1a_e @ w2t_e^T + b2 (unchanged R16 structure) ======
__device__ __forceinline__ void dev_gemm2(
    ushort* sA, ushort* sB,
    const ushort* __restrict__ ha,
    const float* __restrict__ b2, const ushort* __restrict__ w2t,
    float* __restrict__ out, int e, int m0, int n0){
  const int tid  = threadIdx.x;
  const int lane = tid & 63;
  const int wv   = tid >> 6;
  const int l15  = lane & 15;
  const int lg   = lane >> 4;
  const int wm   = wv >> 1;
  const int wn   = wv & 1;
  const ushort* w2e = w2t + (size_t)e * H_ * F_;

  f32x4 acc[4][4];
  #pragma unroll
  for (int a = 0; a < 4; ++a)
    #pragma unroll
    for (int b = 0; b < 4; ++b) acc[a][b] = (f32x4){0.f,0.f,0.f,0.f};

  #define G2_STAGE(KK, NB)  {                                                    \
    _Pragma("unroll")                                                            \
    for (int i = 0; i < 2; ++i){                                                 \
      const int r = wv * 16 + i * 64 + (lane >> 2);                              \
      const ushort* ga = ha + (size_t)(m0 + r) * F_ + (KK) * 32 + (lane & 3) * 8;\
      __builtin_amdgcn_global_load_lds((const u32_glb*)(uintptr_t)ga,            \
          (u32_lds*)(uintptr_t)(sA + (NB) * 4096 + r * 32), 16, 0, 0);           \
      const ushort* gb = w2e + (size_t)(n0 + r) * F_ + (KK) * 32 + (lane & 3) * 8;\
      __builtin_amdgcn_global_load_lds((const u32_glb*)(uintptr_t)gb,            \
          (u32_lds*)(uintptr_t)(sB + (NB) * 4096 + r * 32), 16, 0, 0);           \
    } }

  G2_STAGE(0, 0)
  __syncthreads();

  for (int kk = 0; kk < 64; ++kk){
    const int cur = kk & 1, nxt = cur ^ 1;
    if (kk < 63){ G2_STAGE(kk + 1, nxt) }
    bf16x8 af[4], bfr[4];
    #pragma unroll
    for (int mf = 0; mf < 4; ++mf)
      af[mf] = *(const bf16x8*)(sA + cur * 4096 + (wm * 64 + mf * 16 + l15) * 32 + lg * 8);
    #pragma unroll
    for (int nf = 0; nf < 4; ++nf)
      bfr[nf] = *(const bf16x8*)(sB + cur * 4096 + (wn * 64 + nf * 16 + l15) * 32 + lg * 8);
    __builtin_amdgcn_s_setprio(1);
    #pragma unroll
    for (int mf = 0; mf < 4; ++mf)
      #pragma unroll
      for (int nf = 0; nf < 4; ++nf)
        acc[mf][nf] = __builtin_amdgcn_mfma_f32_16x16x32_bf16(af[mf], bfr[nf], acc[mf][nf], 0, 0, 0);
    __builtin_amdgcn_s_setprio(0);
    __syncthreads();
  }

  #pragma unroll
  for (int nf = 0; nf < 4; ++nf){
    const int h  = n0 + wn * 64 + nf * 16 + l15;
    const float bb = b2[e * H_ + h];
    #pragma unroll
    for (int mf = 0; mf < 4; ++mf){
      const int m = m0 + wm * 64 + mf * 16 + lg * 4;
      #pragma unroll
      for (int i = 0; i < 4; ++i){
        const int mm = m + i;
        const size_t grow = ((size_t)(mm >> 11) * 16 + e) * 2048 + (mm & 2047);
        out[grow * H_ + h] = acc[mf][nf][i] + bb;
      }
    }
  }
  #undef G2_STAGE
}

// ================= global wrappers =================
#define SLAB ((size_t)8192 * F_)

__global__ __launch_bounds__(256, 3) void gemm1_gelu(
    const ushort* __restrict__ xbf, const float* __restrict__ b1,
    const ushort* __restrict__ w1t, ushort* __restrict__ h1a, int e0){
  __shared__ ushort sMain[4 * 4096];     // sA = [0..1], sB = [2..3]
  __shared__ ushort sTr[64 * TR_P];      // 16.9 KB transpose scratch
  const int z = blockIdx.z;
  dev_gemm1_pair(sMain, sMain + 2 * 4096, sTr, xbf, b1, w1t,
                 h1a + (size_t)z * SLAB, e0 + z,
                 blockIdx.x * 128, blockIdx.y * 256);
}

__global__ __launch_bounds__(256, 3) void gemm2_k(
    const ushort* __restrict__ h1a, const float* __restrict__ b2,
    const ushort* __restrict__ w2t, float* __restrict__ out, int e0){
  __shared__ ushort sA[2 * 4096];
  __shared__ ushort sB[2 * 4096];
  const int z = blockIdx.z;
  dev_gemm2(sA, sB, h1a + (size_t)z * SLAB, b2, w2t, out, e0 + z,
            blockIdx.x * 128, blockIdx.y * 128);
}

extern "C" void kernel_launch(void* const* d_in, const int* in_sizes, int n_in,
                              void* d_out, int out_size, void* d_ws, size_t ws_size,
                              hipStream_t stream){
  const float *x = nullptr, *b1 = nullptr, *b2 = nullptr;
  const float* w12[2] = {nullptr, nullptr}; int nw = 0;
  for (int i = 0; i < n_in; ++i){
    long sz = (long)in_sizes[i];
    if      (sz == (long)G_ * E_ * C_ * H_) x = (const float*)d_in[i];
    else if (sz == (long)E_ * H_ * F_) { if (nw < 2) w12[nw++] = (const float*)d_in[i]; }
    else if (sz == (long)E_ * F_) b1 = (const float*)d_in[i];
    else if (sz == (long)E_ * H_) b2 = (const float*)d_in[i];
  }
  const float* w1 = w12[0];
  const float* w2 = w12[1];
  if (!x || !w1 || !w2 || !b1 || !b2){
    x  = (const float*)d_in[0];
    w1 = (const float*)d_in[1];
    b1 = (const float*)d_in[2];
    w2 = (const float*)d_in[3];
    b2 = (const float*)d_in[4];
  }

  // ws layout: w1t | w2t | xbf | h1a slabs
  ushort* w1t = (ushort*)d_ws;                         // 33.5 MB
  ushort* w2t = w1t + (size_t)E_ * F_ * H_;            // 33.5 MB
  ushort* xbf = w2t + (size_t)E_ * H_ * F_;            // 134 MB
  ushort* h1a = xbf + (size_t)G_ * E_ * C_ * H_;       // slabs
  float*  out = (float*)d_out;

  const size_t fixedE = (size_t)2 * E_ * F_ * H_ + (size_t)G_ * E_ * C_ * H_;
  size_t availE = ws_size / 2;
  int nslab = (availE > fixedE) ? (int)((availE - fixedE) / SLAB) : 0;

  transpose_cvt<<<dim3(F_ / 64, H_ / 64, E_), dim3(256), 0, stream>>>(w1, w1t, H_, F_);
  transpose_cvt<<<dim3(H_ / 64, F_ / 64, E_), dim3(256), 0, stream>>>(w2, w2t, F_, H_);
  cvt_x<<<dim3(2048), dim3(256), 0, stream>>>(x, xbf);

  if (nslab >= 16){
    gemm1_gelu<<<dim3(64, 8, 16), dim3(256), 0, stream>>>(xbf, b1, w1t, h1a, 0);
    gemm2_k  <<<dim3(64, 4, 16), dim3(256), 0, stream>>>(h1a, b2, w2t, out, 0);
  } else {
    for (int e0 = 0; e0 < E_; e0 += 2){
      gemm1_gelu<<<dim3(64, 8, 2), dim3(256), 0, stream>>>(xbf, b1, w1t, h1a, e0);
      gemm2_k  <<<dim3(64, 4, 2), dim3(256), 0, stream>>>(h1a, b2, w2t, out, e0);
    }
  }
}

// Round 18
// 929.490 us; speedup vs baseline: 1.1484x; 1.1484x over previous
//
#include <hip/hip_runtime.h>
#include <hip/hip_bf16.h>
#include <stdint.h>

#define G_ 4
#define E_ 16
#define C_ 2048
#define H_ 512
#define F_ 2048

typedef __attribute__((ext_vector_type(8))) short bf16x8;
typedef __attribute__((ext_vector_type(4))) float f32x4;
typedef uint32_t u32_glb __attribute__((address_space(1)));
typedef uint32_t u32_lds __attribute__((address_space(3)));

__device__ __forceinline__ ushort f2bf(float f){
  uint u = __float_as_uint(f);
  return (ushort)((u + 0x7FFFu + ((u >> 16) & 1u)) >> 16);  // RNE
}

__device__ __forceinline__ bf16x8 pack8(f32x4 a, f32x4 b){
  union { bf16x8 v; uint u[4]; } p;
  p.u[0] = (uint)f2bf(a[0]) | ((uint)f2bf(a[1]) << 16);
  p.u[1] = (uint)f2bf(a[2]) | ((uint)f2bf(a[3]) << 16);
  p.u[2] = (uint)f2bf(b[0]) | ((uint)f2bf(b[1]) << 16);
  p.u[3] = (uint)f2bf(b[2]) | ((uint)f2bf(b[3]) << 16);
  return p.v;
}

// fast GELU (R10-validated: absmax 1.95e-3 same as exact-erf version)
__device__ __forceinline__ float geluf(float t){
  float y = 0.7978845608f * t * (1.0f + 0.044715f * t * t);
  y = fminf(fmaxf(y, -9.0f), 9.0f);
  float z = __expf(-2.0f * y);
  return t * __builtin_amdgcn_rcpf(1.0f + z);
}

// transpose + fp32->bf16 convert: src [E][R][C] fp32 -> dst [E][C][R] bf16
__global__ void transpose_cvt(const float* __restrict__ src, ushort* __restrict__ dst,
                              int R, int C){
  __shared__ float tile[64][65];
  int c0 = blockIdx.x * 64, r0 = blockIdx.y * 64, e = blockIdx.z;
  int tx = threadIdx.x & 63, ty = threadIdx.x >> 6;   // 256 threads
  const float* s = src + (size_t)e * R * C;
  #pragma unroll
  for (int it = 0; it < 16; ++it){
    int row = ty + it * 4;
    tile[row][tx] = s[(size_t)(r0 + row) * C + (c0 + tx)];
  }
  __syncthreads();
  ushort* d = dst + (size_t)e * C * R;
  #pragma unroll
  for (int it = 0; it < 16; ++it){
    int row = ty + it * 4;
    d[(size_t)(c0 + row) * R + (r0 + tx)] = f2bf(tile[tx][row]);
  }
}

// X fp32 -> bf16, straight copy (memory-bound)
__global__ __launch_bounds__(256) void cvt_x(const float* __restrict__ x,
                                             ushort* __restrict__ xbf){
  const size_t stride = (size_t)gridDim.x * 256 * 16;
  size_t base = ((size_t)blockIdx.x * 256 + threadIdx.x) * 16;
  for (size_t i = base; i < (size_t)G_ * E_ * C_ * H_; i += stride){
    f32x4 a0 = *(const f32x4*)(x + i);
    f32x4 a1 = *(const f32x4*)(x + i + 4);
    f32x4 a2 = *(const f32x4*)(x + i + 8);
    f32x4 a3 = *(const f32x4*)(x + i + 12);
    *(bf16x8*)(xbf + i)     = pack8(a0, a1);
    *(bf16x8*)(xbf + i + 8) = pack8(a2, a3);
  }
}

#define TR_P 132   // transpose scratch pitch (ushorts): scatter writes ~2-way max

// ====== GEMM1: h1 = gelu(Xe @ w1t^T + b1). R16 mainloop; overlay-transpose epilogue ======
// sAll: 32.8 KB; sA = sAll[0..8191], sB = sAll[8192..16383]; sTr overlays sAll (dead post-loop).
__device__ __forceinline__ void dev_gemm1(
    ushort* sAll,
    const ushort* __restrict__ xbf, const float* __restrict__ b1,
    const ushort* __restrict__ w1t, ushort* __restrict__ h1slab,
    int e, int m0, int n0){
  ushort* sA = sAll;
  ushort* sB = sAll + 2 * 4096;
  const int tid  = threadIdx.x;
  const int lane = tid & 63;
  const int wv   = tid >> 6;
  const int l15  = lane & 15;
  const int lg   = lane >> 4;
  const int wm   = wv >> 1;
  const int wn   = wv & 1;
  const ushort* w1e = w1t + (size_t)e * F_ * H_;
  const ushort* xe  = xbf + (((size_t)(m0 >> 11) * 16 + e) * 2048 + (m0 & 2047)) * H_;

  f32x4 acc[4][4];
  #pragma unroll
  for (int a = 0; a < 4; ++a)
    #pragma unroll
    for (int b = 0; b < 4; ++b) acc[a][b] = (f32x4){0.f,0.f,0.f,0.f};

  #define G1_STAGE(KK, NB) {                                                     \
    _Pragma("unroll")                                                            \
    for (int i = 0; i < 2; ++i){                                                 \
      const int r = wv * 16 + i * 64 + (lane >> 2);                              \
      const ushort* ga = xe + (size_t)r * H_ + (KK) * 32 + (lane & 3) * 8;       \
      __builtin_amdgcn_global_load_lds((const u32_glb*)(uintptr_t)ga,            \
          (u32_lds*)(uintptr_t)(sA + (NB) * 4096 + r * 32), 16, 0, 0);           \
      const ushort* gb = w1e + (size_t)(n0 + r) * H_ + (KK) * 32 + (lane & 3) * 8;\
      __builtin_amdgcn_global_load_lds((const u32_glb*)(uintptr_t)gb,            \
          (u32_lds*)(uintptr_t)(sB + (NB) * 4096 + r * 32), 16, 0, 0);           \
    } }

  G1_STAGE(0, 0)
  __syncthreads();

  for (int kk = 0; kk < 16; ++kk){
    const int cur = kk & 1, nxt = cur ^ 1;
    if (kk < 15){ G1_STAGE(kk + 1, nxt) }
    bf16x8 af[4], bfr[4];
    #pragma unroll
    for (int mf = 0; mf < 4; ++mf)
      af[mf] = *(const bf16x8*)(sA + cur * 4096 + (wm * 64 + mf * 16 + l15) * 32 + lg * 8);
    #pragma unroll
    for (int nf = 0; nf < 4; ++nf)
      bfr[nf] = *(const bf16x8*)(sB + cur * 4096 + (wn * 64 + nf * 16 + l15) * 32 + lg * 8);
    __builtin_amdgcn_s_setprio(1);
    #pragma unroll
    for (int mf = 0; mf < 4; ++mf)
      #pragma unroll
      for (int nf = 0; nf < 4; ++nf)
        acc[mf][nf] = __builtin_amdgcn_mfma_f32_16x16x32_bf16(af[mf], bfr[nf], acc[mf][nf], 0, 0, 0);
    __builtin_amdgcn_s_setprio(0);
    __syncthreads();                  // final iter: nothing in flight afterwards -> LDS dead
  }

  // ---- epilogue: gelu -> LDS transpose (overlay sAll) -> 256B-coalesced stores ----
  ushort* sTr = sAll;                 // 64 x TR_P ushorts = 16.9 KB of the 32.8 KB region
  float bb[4];
  #pragma unroll
  for (int nf = 0; nf < 4; ++nf)
    bb[nf] = b1[e * F_ + n0 + wn * 64 + nf * 16 + l15];
  #pragma unroll
  for (int rr = 0; rr < 2; ++rr){
    if (wm == rr){
      #pragma unroll
      for (int mf = 0; mf < 4; ++mf)
        #pragma unroll
        for (int nf = 0; nf < 4; ++nf)
          #pragma unroll
          for (int i = 0; i < 4; ++i)
            sTr[(mf * 16 + lg * 4 + i) * TR_P + wn * 64 + nf * 16 + l15] =
                f2bf(geluf(acc[mf][nf][i] + bb[nf]));
    }
    __syncthreads();
    #pragma unroll
    for (int u = 0; u < 4; ++u){
      const int unit = u * 256 + tid;
      const int rl = unit >> 4, seg = unit & 15;
      bf16x8 vv = *(const bf16x8*)(&sTr[rl * TR_P + seg * 8]);
      *(bf16x8*)(&h1slab[(size_t)(m0 + rr * 64 + rl) * F_ + n0 + seg * 8]) = vv;
    }
    __syncthreads();
  }
  #undef G1_STAGE
}

// ====== GEMM2: out_e = h1a_e @ w2t_e^T + b2 (unchanged R16 structure) ======
__device__ __forceinline__ void dev_gemm2(
    ushort* sA, ushort* sB,
    const ushort* __restrict__ ha,
    const float* __restrict__ b2, const ushort* __restrict__ w2t,
    float* __restrict__ out, int e, int m0, int n0){
  const int tid  = threadIdx.x;
  const int lane = tid & 63;
  const int wv   = tid >> 6;
  const int l15  = lane & 15;
  const int lg   = lane >> 4;
  const int wm   = wv >> 1;
  const int wn   = wv & 1;
  const ushort* w2e = w2t + (size_t)e * H_ * F_;

  f32x4 acc[4][4];
  #pragma unroll
  for (int a = 0; a < 4; ++a)
    #pragma unroll
    for (int b = 0; b < 4; ++b) acc[a][b] = (f32x4){0.f,0.f,0.f,0.f};

  #define G2_STAGE(KK, NB)  {                                                    \
    _Pragma("unroll")                                                            \
    for (int i = 0; i < 2; ++i){                                                 \
      const int r = wv * 16 + i * 64 + (lane >> 2);                              \
      const ushort* ga = ha + (size_t)(m0 + r) * F_ + (KK) * 32 + (lane & 3) * 8;\
      __builtin_amdgcn_global_load_lds((const u32_glb*)(uintptr_t)ga,            \
          (u32_lds*)(uintptr_t)(sA + (NB) * 4096 + r * 32), 16, 0, 0);           \
      const ushort* gb = w2e + (size_t)(n0 + r) * F_ + (KK) * 32 + (lane & 3) * 8;\
      __builtin_amdgcn_global_load_lds((const u32_glb*)(uintptr_t)gb,            \
          (u32_lds*)(uintptr_t)(sB + (NB) * 4096 + r * 32), 16, 0, 0);           \
    } }

  G2_STAGE(0, 0)
  __syncthreads();

  for (int kk = 0; kk < 64; ++kk){
    const int cur = kk & 1, nxt = cur ^ 1;
    if (kk < 63){ G2_STAGE(kk + 1, nxt) }
    bf16x8 af[4], bfr[4];
    #pragma unroll
    for (int mf = 0; mf < 4; ++mf)
      af[mf] = *(const bf16x8*)(sA + cur * 4096 + (wm * 64 + mf * 16 + l15) * 32 + lg * 8);
    #pragma unroll
    for (int nf = 0; nf < 4; ++nf)
      bfr[nf] = *(const bf16x8*)(sB + cur * 4096 + (wn * 64 + nf * 16 + l15) * 32 + lg * 8);
    __builtin_amdgcn_s_setprio(1);
    #pragma unroll
    for (int mf = 0; mf < 4; ++mf)
      #pragma unroll
      for (int nf = 0; nf < 4; ++nf)
        acc[mf][nf] = __builtin_amdgcn_mfma_f32_16x16x32_bf16(af[mf], bfr[nf], acc[mf][nf], 0, 0, 0);
    __builtin_amdgcn_s_setprio(0);
    __syncthreads();
  }

  #pragma unroll
  for (int nf = 0; nf < 4; ++nf){
    const int h  = n0 + wn * 64 + nf * 16 + l15;
    const float bb = b2[e * H_ + h];
    #pragma unroll
    for (int mf = 0; mf < 4; ++mf){
      const int m = m0 + wm * 64 + mf * 16 + lg * 4;
      #pragma unroll
      for (int i = 0; i < 4; ++i){
        const int mm = m + i;
        const size_t grow = ((size_t)(mm >> 11) * 16 + e) * 2048 + (mm & 2047);
        out[grow * H_ + h] = acc[mf][nf][i] + bb;
      }
    }
  }
  #undef G2_STAGE
}

// ================= global wrappers =================
#define SLAB ((size_t)8192 * F_)

__global__ __launch_bounds__(256, 3) void gemm1_gelu(
    const ushort* __restrict__ xbf, const float* __restrict__ b1,
    const ushort* __restrict__ w1t, ushort* __restrict__ h1a, int e0){
  __shared__ ushort sAll[4 * 4096];   // sA dbuf | sB dbuf; sTr overlays post-loop
  const int z = blockIdx.z;
  dev_gemm1(sAll, xbf, b1, w1t, h1a + (size_t)z * SLAB, e0 + z,
            blockIdx.x * 128, blockIdx.y * 128);
}

__global__ __launch_bounds__(256, 3) void gemm2_k(
    const ushort* __restrict__ h1a, const float* __restrict__ b2,
    const ushort* __restrict__ w2t, float* __restrict__ out, int e0){
  __shared__ ushort sA[2 * 4096];
  __shared__ ushort sB[2 * 4096];
  const int z = blockIdx.z;
  dev_gemm2(sA, sB, h1a + (size_t)z * SLAB, b2, w2t, out, e0 + z,
            blockIdx.x * 128, blockIdx.y * 128);
}

extern "C" void kernel_launch(void* const* d_in, const int* in_sizes, int n_in,
                              void* d_out, int out_size, void* d_ws, size_t ws_size,
                              hipStream_t stream){
  const float *x = nullptr, *b1 = nullptr, *b2 = nullptr;
  const float* w12[2] = {nullptr, nullptr}; int nw = 0;
  for (int i = 0; i < n_in; ++i){
    long sz = (long)in_sizes[i];
    if      (sz == (long)G_ * E_ * C_ * H_) x = (const float*)d_in[i];
    else if (sz == (long)E_ * H_ * F_) { if (nw < 2) w12[nw++] = (const float*)d_in[i]; }
    else if (sz == (long)E_ * F_) b1 = (const float*)d_in[i];
    else if (sz == (long)E_ * H_) b2 = (const float*)d_in[i];
  }
  const float* w1 = w12[0];
  const float* w2 = w12[1];
  if (!x || !w1 || !w2 || !b1 || !b2){
    x  = (const float*)d_in[0];
    w1 = (const float*)d_in[1];
    b1 = (const float*)d_in[2];
    w2 = (const float*)d_in[3];
    b2 = (const float*)d_in[4];
  }

  // ws layout: w1t | w2t | xbf | h1a slabs
  ushort* w1t = (ushort*)d_ws;                         // 33.5 MB
  ushort* w2t = w1t + (size_t)E_ * F_ * H_;            // 33.5 MB
  ushort* xbf = w2t + (size_t)E_ * H_ * F_;            // 134 MB
  ushort* h1a = xbf + (size_t)G_ * E_ * C_ * H_;       // slabs
  float*  out = (float*)d_out;

  const size_t fixedE = (size_t)2 * E_ * F_ * H_ + (size_t)G_ * E_ * C_ * H_;
  size_t availE = ws_size / 2;
  int nslab = (availE > fixedE) ? (int)((availE - fixedE) / SLAB) : 0;

  transpose_cvt<<<dim3(F_ / 64, H_ / 64, E_), dim3(256), 0, stream>>>(w1, w1t, H_, F_);
  transpose_cvt<<<dim3(H_ / 64, F_ / 64, E_), dim3(256), 0, stream>>>(w2, w2t, F_, H_);
  cvt_x<<<dim3(2048), dim3(256), 0, stream>>>(x, xbf);

  if (nslab >= 16){
    gemm1_gelu<<<dim3(64, 16, 16), dim3(256), 0, stream>>>(xbf, b1, w1t, h1a, 0);
    gemm2_k  <<<dim3(64,  4, 16), dim3(256), 0, stream>>>(h1a, b2, w2t, out, 0);
  } else {
    for (int e0 = 0; e0 < E_; e0 += 2){
      gemm1_gelu<<<dim3(64, 16, 2), dim3(256), 0, stream>>>(xbf, b1, w1t, h1a, e0);
      gemm2_k  <<<dim3(64,  4, 2), dim3(256), 0, stream>>>(h1a, b2, w2t, out, e0);
    }
  }
}

// Round 19
// 894.902 us; speedup vs baseline: 1.1927x; 1.0386x over previous
//
#include <hip/hip_runtime.h>
#include <hip/hip_bf16.h>
#include <stdint.h>

#define G_ 4
#define E_ 16
#define C_ 2048
#define H_ 512
#define F_ 2048

typedef __attribute__((ext_vector_type(8))) short bf16x8;
typedef __attribute__((ext_vector_type(4))) float f32x4;
typedef uint32_t u32_glb __attribute__((address_space(1)));
typedef uint32_t u32_lds __attribute__((address_space(3)));

__device__ __forceinline__ ushort f2bf(float f){
  uint u = __float_as_uint(f);
  return (ushort)((u + 0x7FFFu + ((u >> 16) & 1u)) >> 16);  // RNE
}

__device__ __forceinline__ bf16x8 pack8(f32x4 a, f32x4 b){
  union { bf16x8 v; uint u[4]; } p;
  p.u[0] = (uint)f2bf(a[0]) | ((uint)f2bf(a[1]) << 16);
  p.u[1] = (uint)f2bf(a[2]) | ((uint)f2bf(a[3]) << 16);
  p.u[2] = (uint)f2bf(b[0]) | ((uint)f2bf(b[1]) << 16);
  p.u[3] = (uint)f2bf(b[2]) | ((uint)f2bf(b[3]) << 16);
  return p.v;
}

// fast GELU (R10-validated: absmax 1.95e-3 same as exact-erf version)
__device__ __forceinline__ float geluf(float t){
  float y = 0.7978845608f * t * (1.0f + 0.044715f * t * t);
  y = fminf(fmaxf(y, -9.0f), 9.0f);
  float z = __expf(-2.0f * y);
  return t * __builtin_amdgcn_rcpf(1.0f + z);
}

// transpose + fp32->bf16 convert: src [E][R][C] fp32 -> dst [E][C][R] bf16
__global__ void transpose_cvt(const float* __restrict__ src, ushort* __restrict__ dst,
                              int R, int C){
  __shared__ float tile[64][65];
  int c0 = blockIdx.x * 64, r0 = blockIdx.y * 64, e = blockIdx.z;
  int tx = threadIdx.x & 63, ty = threadIdx.x >> 6;   // 256 threads
  const float* s = src + (size_t)e * R * C;
  #pragma unroll
  for (int it = 0; it < 16; ++it){
    int row = ty + it * 4;
    tile[row][tx] = s[(size_t)(r0 + row) * C + (c0 + tx)];
  }
  __syncthreads();
  ushort* d = dst + (size_t)e * C * R;
  #pragma unroll
  for (int it = 0; it < 16; ++it){
    int row = ty + it * 4;
    d[(size_t)(c0 + row) * R + (r0 + tx)] = f2bf(tile[tx][row]);
  }
}

// X fp32 -> bf16, straight copy (memory-bound)
__global__ __launch_bounds__(256) void cvt_x(const float* __restrict__ x,
                                             ushort* __restrict__ xbf){
  const size_t stride = (size_t)gridDim.x * 256 * 16;
  size_t base = ((size_t)blockIdx.x * 256 + threadIdx.x) * 16;
  for (size_t i = base; i < (size_t)G_ * E_ * C_ * H_; i += stride){
    f32x4 a0 = *(const f32x4*)(x + i);
    f32x4 a1 = *(const f32x4*)(x + i + 4);
    f32x4 a2 = *(const f32x4*)(x + i + 8);
    f32x4 a3 = *(const f32x4*)(x + i + 12);
    *(bf16x8*)(xbf + i)     = pack8(a0, a1);
    *(bf16x8*)(xbf + i + 8) = pack8(a2, a3);
  }
}

#define TR_P 132   // transpose scratch pitch (ushorts)

// counted-vmcnt barrier: stage(t+1) retired, stage(t+2) stays in flight
#define PIPE_BARRIER(COND_DEEP)                                                  \
  { if (COND_DEEP) { asm volatile("s_waitcnt vmcnt(4)" ::: "memory"); }          \
    else           { asm volatile("s_waitcnt vmcnt(0)" ::: "memory"); }          \
    asm volatile("s_waitcnt lgkmcnt(0)" ::: "memory");                           \
    __builtin_amdgcn_s_barrier(); }

// ====== GEMM1: h1 = gelu(Xe @ w1t^T + b1). Triple-buffered m97 loop; parallel epilogue ======
// sAll: 48 KB = A bufs [3][4096] | B bufs [3][4096] (ushorts); sTr overlays post-loop.
__device__ __forceinline__ void dev_gemm1(
    ushort* sAll,
    const ushort* __restrict__ xbf, const float* __restrict__ b1,
    const ushort* __restrict__ w1t, ushort* __restrict__ h1slab,
    int e, int m0, int n0){
  ushort* sA = sAll;
  ushort* sB = sAll + 3 * 4096;
  const int tid  = threadIdx.x;
  const int lane = tid & 63;
  const int wv   = tid >> 6;
  const int l15  = lane & 15;
  const int lg   = lane >> 4;
  const int wm   = wv >> 1;
  const int wn   = wv & 1;
  const ushort* w1e = w1t + (size_t)e * F_ * H_;
  const ushort* xe  = xbf + (((size_t)(m0 >> 11) * 16 + e) * 2048 + (m0 & 2047)) * H_;

  f32x4 acc[4][4];
  #pragma unroll
  for (int a = 0; a < 4; ++a)
    #pragma unroll
    for (int b = 0; b < 4; ++b) acc[a][b] = (f32x4){0.f,0.f,0.f,0.f};

  #define G1_STAGE(KK, NB) {                                                     \
    _Pragma("unroll")                                                            \
    for (int i = 0; i < 2; ++i){                                                 \
      const int r = wv * 16 + i * 64 + (lane >> 2);                              \
      const ushort* ga = xe + (size_t)r * H_ + (KK) * 32 + (lane & 3) * 8;       \
      __builtin_amdgcn_global_load_lds((const u32_glb*)(uintptr_t)ga,            \
          (u32_lds*)(uintptr_t)(sA + (NB) * 4096 + r * 32), 16, 0, 0);           \
      const ushort* gb = w1e + (size_t)(n0 + r) * H_ + (KK) * 32 + (lane & 3) * 8;\
      __builtin_amdgcn_global_load_lds((const u32_glb*)(uintptr_t)gb,            \
          (u32_lds*)(uintptr_t)(sB + (NB) * 4096 + r * 32), 16, 0, 0);           \
    } }

  // prologue: stage k0,k1 (8 loads/thread); wait stage0 landed (vmcnt 8->4)
  G1_STAGE(0, 0)
  G1_STAGE(1, 1)
  asm volatile("s_waitcnt vmcnt(4)" ::: "memory");
  __builtin_amdgcn_s_barrier();

  for (int kk = 0; kk < 16; ++kk){
    const int cur = kk % 3;
    if (kk <= 13){
      int nst = cur + 2; if (nst >= 3) nst -= 3;
      G1_STAGE(kk + 2, nst)
    }
    bf16x8 af[4], bfr[4];
    #pragma unroll
    for (int mf = 0; mf < 4; ++mf)
      af[mf] = *(const bf16x8*)(sA + cur * 4096 + (wm * 64 + mf * 16 + l15) * 32 + lg * 8);
    #pragma unroll
    for (int nf = 0; nf < 4; ++nf)
      bfr[nf] = *(const bf16x8*)(sB + cur * 4096 + (wn * 64 + nf * 16 + l15) * 32 + lg * 8);
    __builtin_amdgcn_s_setprio(1);
    #pragma unroll
    for (int mf = 0; mf < 4; ++mf)
      #pragma unroll
      for (int nf = 0; nf < 4; ++nf)
        acc[mf][nf] = __builtin_amdgcn_mfma_f32_16x16x32_bf16(af[mf], bfr[nf], acc[mf][nf], 0, 0, 0);
    __builtin_amdgcn_s_setprio(0);
    PIPE_BARRIER(kk <= 13)
  }

  // ---- epilogue: both halves transpose concurrently (overlay), 1 barrier, coalesced stores
  ushort* sTr = sAll;                 // [2][64][TR_P] = 33.8 KB of the 48 KB region
  {
    float bb[4];
    #pragma unroll
    for (int nf = 0; nf < 4; ++nf)
      bb[nf] = b1[e * F_ + n0 + wn * 64 + nf * 16 + l15];
    ushort* myTr = sTr + wm * (64 * TR_P);
    #pragma unroll
    for (int mf = 0; mf < 4; ++mf)
      #pragma unroll
      for (int nf = 0; nf < 4; ++nf)
        #pragma unroll
        for (int i = 0; i < 4; ++i)
          myTr[(mf * 16 + lg * 4 + i) * TR_P + wn * 64 + nf * 16 + l15] =
              f2bf(geluf(acc[mf][nf][i] + bb[nf]));
  }
  __syncthreads();
  #pragma unroll
  for (int u = 0; u < 8; ++u){
    const int unit = u * 256 + tid;
    const int rl = unit >> 4, seg = unit & 15;       // row 0..127, 16B-seg 0..15
    bf16x8 vv = *(const bf16x8*)(&sTr[(rl >> 6) * (64 * TR_P) + (rl & 63) * TR_P + seg * 8]);
    *(bf16x8*)(&h1slab[(size_t)(m0 + rl) * F_ + n0 + seg * 8]) = vv;
  }
  #undef G1_STAGE
}

// ====== GEMM2: out_e = h1a_e @ w2t_e^T + b2. Triple-buffered, counted vmcnt ======
__device__ __forceinline__ void dev_gemm2(
    ushort* sA, ushort* sB,
    const ushort* __restrict__ ha,
    const float* __restrict__ b2, const ushort* __restrict__ w2t,
    float* __restrict__ out, int e, int m0, int n0){
  const int tid  = threadIdx.x;
  const int lane = tid & 63;
  const int wv   = tid >> 6;
  const int l15  = lane & 15;
  const int lg   = lane >> 4;
  const int wm   = wv >> 1;
  const int wn   = wv & 1;
  const ushort* w2e = w2t + (size_t)e * H_ * F_;

  f32x4 acc[4][4];
  #pragma unroll
  for (int a = 0; a < 4; ++a)
    #pragma unroll
    for (int b = 0; b < 4; ++b) acc[a][b] = (f32x4){0.f,0.f,0.f,0.f};

  #define G2_STAGE(KK, NB)  {                                                    \
    _Pragma("unroll")                                                            \
    for (int i = 0; i < 2; ++i){                                                 \
      const int r = wv * 16 + i * 64 + (lane >> 2);                              \
      const ushort* ga = ha + (size_t)(m0 + r) * F_ + (KK) * 32 + (lane & 3) * 8;\
      __builtin_amdgcn_global_load_lds((const u32_glb*)(uintptr_t)ga,            \
          (u32_lds*)(uintptr_t)(sA + (NB) * 4096 + r * 32), 16, 0, 0);           \
      const ushort* gb = w2e + (size_t)(n0 + r) * F_ + (KK) * 32 + (lane & 3) * 8;\
      __builtin_amdgcn_global_load_lds((const u32_glb*)(uintptr_t)gb,            \
          (u32_lds*)(uintptr_t)(sB + (NB) * 4096 + r * 32), 16, 0, 0);           \
    } }

  G2_STAGE(0, 0)
  G2_STAGE(1, 1)
  asm volatile("s_waitcnt vmcnt(4)" ::: "memory");
  __builtin_amdgcn_s_barrier();

  for (int kk = 0; kk < 64; ++kk){
    const int cur = kk % 3;
    if (kk <= 61){
      int nst = cur + 2; if (nst >= 3) nst -= 3;
      G2_STAGE(kk + 2, nst)
    }
    bf16x8 af[4], bfr[4];
    #pragma unroll
    for (int mf = 0; mf < 4; ++mf)
      af[mf] = *(const bf16x8*)(sA + cur * 4096 + (wm * 64 + mf * 16 + l15) * 32 + lg * 8);
    #pragma unroll
    for (int nf = 0; nf < 4; ++nf)
      bfr[nf] = *(const bf16x8*)(sB + cur * 4096 + (wn * 64 + nf * 16 + l15) * 32 + lg * 8);
    __builtin_amdgcn_s_setprio(1);
    #pragma unroll
    for (int mf = 0; mf < 4; ++mf)
      #pragma unroll
      for (int nf = 0; nf < 4; ++nf)
        acc[mf][nf] = __builtin_amdgcn_mfma_f32_16x16x32_bf16(af[mf], bfr[nf], acc[mf][nf], 0, 0, 0);
    __builtin_amdgcn_s_setprio(0);
    PIPE_BARRIER(kk <= 61)
  }

  #pragma unroll
  for (int nf = 0; nf < 4; ++nf){
    const int h  = n0 + wn * 64 + nf * 16 + l15;
    const float bb = b2[e * H_ + h];
    #pragma unroll
    for (int mf = 0; mf < 4; ++mf){
      const int m = m0 + wm * 64 + mf * 16 + lg * 4;
      #pragma unroll
      for (int i = 0; i < 4; ++i){
        const int mm = m + i;
        const size_t grow = ((size_t)(mm >> 11) * 16 + e) * 2048 + (mm & 2047);
        out[grow * H_ + h] = acc[mf][nf][i] + bb;
      }
    }
  }
  #undef G2_STAGE
}

// ================= global wrappers =================
#define SLAB ((size_t)8192 * F_)

__global__ __launch_bounds__(256, 3) void gemm1_gelu(
    const ushort* __restrict__ xbf, const float* __restrict__ b1,
    const ushort* __restrict__ w1t, ushort* __restrict__ h1a, int e0){
  __shared__ ushort sAll[6 * 4096];   // 48 KB: A[3] | B[3]; sTr overlays post-loop
  const int z = blockIdx.z;
  dev_gemm1(sAll, xbf, b1, w1t, h1a + (size_t)z * SLAB, e0 + z,
            blockIdx.x * 128, blockIdx.y * 128);
}

__global__ __launch_bounds__(256, 3) void gemm2_k(
    const ushort* __restrict__ h1a, const float* __restrict__ b2,
    const ushort* __restrict__ w2t, float* __restrict__ out, int e0){
  __shared__ ushort sA[3 * 4096];
  __shared__ ushort sB[3 * 4096];
  const int z = blockIdx.z;
  dev_gemm2(sA, sB, h1a + (size_t)z * SLAB, b2, w2t, out, e0 + z,
            blockIdx.x * 128, blockIdx.y * 128);
}

extern "C" void kernel_launch(void* const* d_in, const int* in_sizes, int n_in,
                              void* d_out, int out_size, void* d_ws, size_t ws_size,
                              hipStream_t stream){
  const float *x = nullptr, *b1 = nullptr, *b2 = nullptr;
  const float* w12[2] = {nullptr, nullptr}; int nw = 0;
  for (int i = 0; i < n_in; ++i){
    long sz = (long)in_sizes[i];
    if      (sz == (long)G_ * E_ * C_ * H_) x = (const float*)d_in[i];
    else if (sz == (long)E_ * H_ * F_) { if (nw < 2) w12[nw++] = (const float*)d_in[i]; }
    else if (sz == (long)E_ * F_) b1 = (const float*)d_in[i];
    else if (sz == (long)E_ * H_) b2 = (const float*)d_in[i];
  }
  const float* w1 = w12[0];
  const float* w2 = w12[1];
  if (!x || !w1 || !w2 || !b1 || !b2){
    x  = (const float*)d_in[0];
    w1 = (const float*)d_in[1];
    b1 = (const float*)d_in[2];
    w2 = (const float*)d_in[3];
    b2 = (const float*)d_in[4];
  }

  // ws layout: w1t | w2t | xbf | h1a slabs
  ushort* w1t = (ushort*)d_ws;                         // 33.5 MB
  ushort* w2t = w1t + (size_t)E_ * F_ * H_;            // 33.5 MB
  ushort* xbf = w2t + (size_t)E_ * H_ * F_;            // 134 MB
  ushort* h1a = xbf + (size_t)G_ * E_ * C_ * H_;       // slabs
  float*  out = (float*)d_out;

  const size_t fixedE = (size_t)2 * E_ * F_ * H_ + (size_t)G_ * E_ * C_ * H_;
  size_t availE = ws_size / 2;
  int nslab = (availE > fixedE) ? (int)((availE - fixedE) / SLAB) : 0;

  transpose_cvt<<<dim3(F_ / 64, H_ / 64, E_), dim3(256), 0, stream>>>(w1, w1t, H_, F_);
  transpose_cvt<<<dim3(H_ / 64, F_ / 64, E_), dim3(256), 0, stream>>>(w2, w2t, F_, H_);
  cvt_x<<<dim3(2048), dim3(256), 0, stream>>>(x, xbf);

  if (nslab >= 16){
    gemm1_gelu<<<dim3(64, 16, 16), dim3(256), 0, stream>>>(xbf, b1, w1t, h1a, 0);
    gemm2_k  <<<dim3(64,  4, 16), dim3(256), 0, stream>>>(h1a, b2, w2t, out, 0);
  } else {
    for (int e0 = 0; e0 < E_; e0 += 2){
      gemm1_gelu<<<dim3(64, 16, 2), dim3(256), 0, stream>>>(xbf, b1, w1t, h1a, e0);
      gemm2_k  <<<dim3(64,  4, 2), dim3(256), 0, stream>>>(h1a, b2, w2t, out, e0);
    }
  }
}

// Round 20
// 894.832 us; speedup vs baseline: 1.1928x; 1.0001x over previous
//
#include <hip/hip_runtime.h>
#include <hip/hip_bf16.h>
#include <stdint.h>

#define G_ 4
#define E_ 16
#define C_ 2048
#define H_ 512
#define F_ 2048

typedef __attribute__((ext_vector_type(8))) short bf16x8;
typedef __attribute__((ext_vector_type(4))) float f32x4;
typedef uint32_t u32_glb __attribute__((address_space(1)));
typedef uint32_t u32_lds __attribute__((address_space(3)));

__device__ __forceinline__ ushort f2bf(float f){
  uint u = __float_as_uint(f);
  return (ushort)((u + 0x7FFFu + ((u >> 16) & 1u)) >> 16);  // RNE
}

__device__ __forceinline__ bf16x8 pack8(f32x4 a, f32x4 b){
  union { bf16x8 v; uint u[4]; } p;
  p.u[0] = (uint)f2bf(a[0]) | ((uint)f2bf(a[1]) << 16);
  p.u[1] = (uint)f2bf(a[2]) | ((uint)f2bf(a[3]) << 16);
  p.u[2] = (uint)f2bf(b[0]) | ((uint)f2bf(b[1]) << 16);
  p.u[3] = (uint)f2bf(b[2]) | ((uint)f2bf(b[3]) << 16);
  return p.v;
}

// fast GELU (R10-validated: absmax 1.95e-3 same as exact-erf version)
__device__ __forceinline__ float geluf(float t){
  float y = 0.7978845608f * t * (1.0f + 0.044715f * t * t);
  y = fminf(fmaxf(y, -9.0f), 9.0f);
  float z = __expf(-2.0f * y);
  return t * __builtin_amdgcn_rcpf(1.0f + z);
}

// ---- device bodies for prep ----
__device__ __forceinline__ void dev_transpose(
    float (*tile)[65], const float* __restrict__ src, ushort* __restrict__ dst,
    int R, int C, int c0, int r0, int e){
  int tx = threadIdx.x & 63, ty = threadIdx.x >> 6;   // 256 threads
  const float* s = src + (size_t)e * R * C;
  #pragma unroll
  for (int it = 0; it < 16; ++it){
    int row = ty + it * 4;
    tile[row][tx] = s[(size_t)(r0 + row) * C + (c0 + tx)];
  }
  __syncthreads();
  ushort* d = dst + (size_t)e * C * R;
  #pragma unroll
  for (int it = 0; it < 16; ++it){
    int row = ty + it * 4;
    d[(size_t)(c0 + row) * R + (r0 + tx)] = f2bf(tile[tx][row]);
  }
}

__device__ __forceinline__ void dev_cvtx(const float* __restrict__ x,
                                         ushort* __restrict__ xbf, int bid){
  const size_t stride = (size_t)2048 * 256 * 16;
  size_t base = ((size_t)bid * 256 + threadIdx.x) * 16;
  for (size_t i = base; i < (size_t)G_ * E_ * C_ * H_; i += stride){
    f32x4 a0 = *(const f32x4*)(x + i);
    f32x4 a1 = *(const f32x4*)(x + i + 4);
    f32x4 a2 = *(const f32x4*)(x + i + 8);
    f32x4 a3 = *(const f32x4*)(x + i + 12);
    *(bf16x8*)(xbf + i)     = pack8(a0, a1);
    *(bf16x8*)(xbf + i + 8) = pack8(a2, a3);
  }
}

// prep_all: [0,4096) w1 transpose; [4096,6144) cvt_x
__global__ __launch_bounds__(256) void prep_all(
    const float* __restrict__ x, const float* __restrict__ w1,
    ushort* __restrict__ w1t, ushort* __restrict__ xbf){
  __shared__ float tile[64][65];
  const int b = blockIdx.x;
  if (b < 4096){
    dev_transpose(tile, w1, w1t, H_, F_, (b & 31) * 64, ((b >> 5) & 7) * 64, b >> 8);
  } else {
    dev_cvtx(x, xbf, b - 4096);
  }
}

// standalone w2 transpose (fallback path only)
__global__ __launch_bounds__(256) void transpose_w2(
    const float* __restrict__ w2, ushort* __restrict__ w2t){
  __shared__ float tile[64][65];
  const int t = blockIdx.x;
  dev_transpose(tile, w2, w2t, F_, H_, (t & 7) * 64, ((t >> 3) & 31) * 64, t >> 8);
}

#define TR_P 132   // transpose scratch pitch (ushorts)

// counted-vmcnt barrier: stage(t+1) retired, stage(t+2) stays in flight
#define PIPE_BARRIER(COND_DEEP)                                                  \
  { if (COND_DEEP) { asm volatile("s_waitcnt vmcnt(4)" ::: "memory"); }          \
    else           { asm volatile("s_waitcnt vmcnt(0)" ::: "memory"); }          \
    asm volatile("s_waitcnt lgkmcnt(0)" ::: "memory");                           \
    __builtin_amdgcn_s_barrier(); }

// ====== GEMM1: h1 = gelu(Xe @ w1t^T + b1). Triple-buffered m97 loop (R19-proven) ======
__device__ __forceinline__ void dev_gemm1(
    ushort* sAll,
    const ushort* __restrict__ xbf, const float* __restrict__ b1,
    const ushort* __restrict__ w1t, ushort* __restrict__ h1slab,
    int e, int m0, int n0){
  ushort* sA = sAll;
  ushort* sB = sAll + 3 * 4096;
  const int tid  = threadIdx.x;
  const int lane = tid & 63;
  const int wv   = tid >> 6;
  const int l15  = lane & 15;
  const int lg   = lane >> 4;
  const int wm   = wv >> 1;
  const int wn   = wv & 1;
  const ushort* w1e = w1t + (size_t)e * F_ * H_;
  const ushort* xe  = xbf + (((size_t)(m0 >> 11) * 16 + e) * 2048 + (m0 & 2047)) * H_;

  f32x4 acc[4][4];
  #pragma unroll
  for (int a = 0; a < 4; ++a)
    #pragma unroll
    for (int b = 0; b < 4; ++b) acc[a][b] = (f32x4){0.f,0.f,0.f,0.f};

  #define G1_STAGE(KK, NB) {                                                     \
    _Pragma("unroll")                                                            \
    for (int i = 0; i < 2; ++i){                                                 \
      const int r = wv * 16 + i * 64 + (lane >> 2);                              \
      const ushort* ga = xe + (size_t)r * H_ + (KK) * 32 + (lane & 3) * 8;       \
      __builtin_amdgcn_global_load_lds((const u32_glb*)(uintptr_t)ga,            \
          (u32_lds*)(uintptr_t)(sA + (NB) * 4096 + r * 32), 16, 0, 0);           \
      const ushort* gb = w1e + (size_t)(n0 + r) * H_ + (KK) * 32 + (lane & 3) * 8;\
      __builtin_amdgcn_global_load_lds((const u32_glb*)(uintptr_t)gb,            \
          (u32_lds*)(uintptr_t)(sB + (NB) * 4096 + r * 32), 16, 0, 0);           \
    } }

  G1_STAGE(0, 0)
  G1_STAGE(1, 1)
  asm volatile("s_waitcnt vmcnt(4)" ::: "memory");
  __builtin_amdgcn_s_barrier();

  for (int kk = 0; kk < 16; ++kk){
    const int cur = kk % 3;
    if (kk <= 13){
      int nst = cur + 2; if (nst >= 3) nst -= 3;
      G1_STAGE(kk + 2, nst)
    }
    bf16x8 af[4], bfr[4];
    #pragma unroll
    for (int mf = 0; mf < 4; ++mf)
      af[mf] = *(const bf16x8*)(sA + cur * 4096 + (wm * 64 + mf * 16 + l15) * 32 + lg * 8);
    #pragma unroll
    for (int nf = 0; nf < 4; ++nf)
      bfr[nf] = *(const bf16x8*)(sB + cur * 4096 + (wn * 64 + nf * 16 + l15) * 32 + lg * 8);
    __builtin_amdgcn_s_setprio(1);
    #pragma unroll
    for (int mf = 0; mf < 4; ++mf)
      #pragma unroll
      for (int nf = 0; nf < 4; ++nf)
        acc[mf][nf] = __builtin_amdgcn_mfma_f32_16x16x32_bf16(af[mf], bfr[nf], acc[mf][nf], 0, 0, 0);
    __builtin_amdgcn_s_setprio(0);
    PIPE_BARRIER(kk <= 13)
  }

  // epilogue: gelu -> LDS transpose (overlay) -> 256B-coalesced stores
  ushort* sTr = sAll;
  {
    float bb[4];
    #pragma unroll
    for (int nf = 0; nf < 4; ++nf)
      bb[nf] = b1[e * F_ + n0 + wn * 64 + nf * 16 + l15];
    ushort* myTr = sTr + wm * (64 * TR_P);
    #pragma unroll
    for (int mf = 0; mf < 4; ++mf)
      #pragma unroll
      for (int nf = 0; nf < 4; ++nf)
        #pragma unroll
        for (int i = 0; i < 4; ++i)
          myTr[(mf * 16 + lg * 4 + i) * TR_P + wn * 64 + nf * 16 + l15] =
              f2bf(geluf(acc[mf][nf][i] + bb[nf]));
  }
  __syncthreads();
  #pragma unroll
  for (int u = 0; u < 8; ++u){
    const int unit = u * 256 + tid;
    const int rl = unit >> 4, seg = unit & 15;
    bf16x8 vv = *(const bf16x8*)(&sTr[(rl >> 6) * (64 * TR_P) + (rl & 63) * TR_P + seg * 8]);
    *(bf16x8*)(&h1slab[(size_t)(m0 + rl) * F_ + n0 + seg * 8]) = vv;
  }
  #undef G1_STAGE
}

// ====== GEMM2: out_e = h1a_e @ w2t_e^T + b2. Triple-buffered (R19-proven) ======
__device__ __forceinline__ void dev_gemm2(
    ushort* sA, ushort* sB,
    const ushort* __restrict__ ha,
    const float* __restrict__ b2, const ushort* __restrict__ w2t,
    float* __restrict__ out, int e, int m0, int n0){
  const int tid  = threadIdx.x;
  const int lane = tid & 63;
  const int wv   = tid >> 6;
  const int l15  = lane & 15;
  const int lg   = lane >> 4;
  const int wm   = wv >> 1;
  const int wn   = wv & 1;
  const ushort* w2e = w2t + (size_t)e * H_ * F_;

  f32x4 acc[4][4];
  #pragma unroll
  for (int a = 0; a < 4; ++a)
    #pragma unroll
    for (int b = 0; b < 4; ++b) acc[a][b] = (f32x4){0.f,0.f,0.f,0.f};

  #define G2_STAGE(KK, NB)  {                                                    \
    _Pragma("unroll")                                                            \
    for (int i = 0; i < 2; ++i){                                                 \
      const int r = wv * 16 + i * 64 + (lane >> 2);                              \
      const ushort* ga = ha + (size_t)(m0 + r) * F_ + (KK) * 32 + (lane & 3) * 8;\
      __builtin_amdgcn_global_load_lds((const u32_glb*)(uintptr_t)ga,            \
          (u32_lds*)(uintptr_t)(sA + (NB) * 4096 + r * 32), 16, 0, 0);           \
      const ushort* gb = w2e + (size_t)(n0 + r) * F_ + (KK) * 32 + (lane & 3) * 8;\
      __builtin_amdgcn_global_load_lds((const u32_glb*)(uintptr_t)gb,            \
          (u32_lds*)(uintptr_t)(sB + (NB) * 4096 + r * 32), 16, 0, 0);           \
    } }

  G2_STAGE(0, 0)
  G2_STAGE(1, 1)
  asm volatile("s_waitcnt vmcnt(4)" ::: "memory");
  __builtin_amdgcn_s_barrier();

  for (int kk = 0; kk < 64; ++kk){
    const int cur = kk % 3;
    if (kk <= 61){
      int nst = cur + 2; if (nst >= 3) nst -= 3;
      G2_STAGE(kk + 2, nst)
    }
    bf16x8 af[4], bfr[4];
    #pragma unroll
    for (int mf = 0; mf < 4; ++mf)
      af[mf] = *(const bf16x8*)(sA + cur * 4096 + (wm * 64 + mf * 16 + l15) * 32 + lg * 8);
    #pragma unroll
    for (int nf = 0; nf < 4; ++nf)
      bfr[nf] = *(const bf16x8*)(sB + cur * 4096 + (wn * 64 + nf * 16 + l15) * 32 + lg * 8);
    __builtin_amdgcn_s_setprio(1);
    #pragma unroll
    for (int mf = 0; mf < 4; ++mf)
      #pragma unroll
      for (int nf = 0; nf < 4; ++nf)
        acc[mf][nf] = __builtin_amdgcn_mfma_f32_16x16x32_bf16(af[mf], bfr[nf], acc[mf][nf], 0, 0, 0);
    __builtin_amdgcn_s_setprio(0);
    PIPE_BARRIER(kk <= 61)
  }

  #pragma unroll
  for (int nf = 0; nf < 4; ++nf){
    const int h  = n0 + wn * 64 + nf * 16 + l15;
    const float bb = b2[e * H_ + h];
    #pragma unroll
    for (int mf = 0; mf < 4; ++mf){
      const int m = m0 + wm * 64 + mf * 16 + lg * 4;
      #pragma unroll
      for (int i = 0; i < 4; ++i){
        const int mm = m + i;
        const size_t grow = ((size_t)(mm >> 11) * 16 + e) * 2048 + (mm & 2047);
        out[grow * H_ + h] = acc[mf][nf][i] + bb;
      }
    }
  }
  #undef G2_STAGE
}

// ================= global wrappers =================
#define SLAB ((size_t)8192 * F_)

// gemm1_fused: [0, NG1) gemm1 tiles (NE experts from e0); [NG1, NG1+4096) w2 transpose (optional)
__global__ __launch_bounds__(256, 3) void gemm1_fused(
    const ushort* __restrict__ xbf, const float* __restrict__ b1,
    const ushort* __restrict__ w1t, ushort* __restrict__ h1a,
    const float* __restrict__ w2, ushort* __restrict__ w2t,
    int e0, int ng1){
  __shared__ ushort sAll[6 * 4096];   // 48 KB (transpose path uses 16.6 KB)
  const int b = blockIdx.x;
  if (b < ng1){
    const int z = b >> 10;            // 1024 tiles per expert
    dev_gemm1(sAll, xbf, b1, w1t, h1a + (size_t)z * SLAB, e0 + z,
              (b & 63) * 128, ((b >> 6) & 15) * 128);
  } else {
    const int t = b - ng1;            // w2: [E][2048][512] -> w2t [E][512][2048]
    dev_transpose((float(*)[65])sAll, w2, w2t, F_, H_,
                  (t & 7) * 64, ((t >> 3) & 31) * 64, t >> 8);
  }
}

__global__ __launch_bounds__(256, 3) void gemm2_k(
    const ushort* __restrict__ h1a, const float* __restrict__ b2,
    const ushort* __restrict__ w2t, float* __restrict__ out, int e0){
  __shared__ ushort sA[3 * 4096];
  __shared__ ushort sB[3 * 4096];
  const int z = blockIdx.z;
  dev_gemm2(sA, sB, h1a + (size_t)z * SLAB, b2, w2t, out, e0 + z,
            blockIdx.x * 128, blockIdx.y * 128);
}

extern "C" void kernel_launch(void* const* d_in, const int* in_sizes, int n_in,
                              void* d_out, int out_size, void* d_ws, size_t ws_size,
                              hipStream_t stream){
  const float *x = nullptr, *b1 = nullptr, *b2 = nullptr;
  const float* w12[2] = {nullptr, nullptr}; int nw = 0;
  for (int i = 0; i < n_in; ++i){
    long sz = (long)in_sizes[i];
    if      (sz == (long)G_ * E_ * C_ * H_) x = (const float*)d_in[i];
    else if (sz == (long)E_ * H_ * F_) { if (nw < 2) w12[nw++] = (const float*)d_in[i]; }
    else if (sz == (long)E_ * F_) b1 = (const float*)d_in[i];
    else if (sz == (long)E_ * H_) b2 = (const float*)d_in[i];
  }
  const float* w1 = w12[0];
  const float* w2 = w12[1];
  if (!x || !w1 || !w2 || !b1 || !b2){
    x  = (const float*)d_in[0];
    w1 = (const float*)d_in[1];
    b1 = (const float*)d_in[2];
    w2 = (const float*)d_in[3];
    b2 = (const float*)d_in[4];
  }

  // ws layout: w1t | w2t | xbf | h1a slabs
  ushort* w1t = (ushort*)d_ws;                         // 33.5 MB
  ushort* w2t = w1t + (size_t)E_ * F_ * H_;            // 33.5 MB
  ushort* xbf = w2t + (size_t)E_ * H_ * F_;            // 134 MB
  ushort* h1a = xbf + (size_t)G_ * E_ * C_ * H_;       // slabs
  float*  out = (float*)d_out;

  const size_t fixedE = (size_t)2 * E_ * F_ * H_ + (size_t)G_ * E_ * C_ * H_;
  size_t availE = ws_size / 2;
  int nslab = (availE > fixedE) ? (int)((availE - fixedE) / SLAB) : 0;

  // launch 1: w1 transpose + x convert (merged)
  prep_all<<<dim3(6144), dim3(256), 0, stream>>>(x, w1, w1t, xbf);

  if (nslab >= 16){
    // launch 2: gemm1 (16 experts) + w2 transpose in the tail
    gemm1_fused<<<dim3(16384 + 4096), dim3(256), 0, stream>>>(
        xbf, b1, w1t, h1a, w2, w2t, 0, 16384);
    // launch 3: gemm2 (16 experts)
    gemm2_k<<<dim3(64, 4, 16), dim3(256), 0, stream>>>(h1a, b2, w2t, out, 0);
  } else {
    // fallback (small ws): w2 transpose standalone, then pairwise
    transpose_w2<<<dim3(4096), dim3(256), 0, stream>>>(w2, w2t);
    for (int e0 = 0; e0 < E_; e0 += 2){
      gemm1_fused<<<dim3(2048), dim3(256), 0, stream>>>(
          xbf, b1, w1t, h1a, w2, w2t, e0, 2048);
      gemm2_k<<<dim3(64, 4, 2), dim3(256), 0, stream>>>(h1a, b2, w2t, out, e0);
    }
  }
}